// Round 8
// baseline (345.830 us; speedup 1.0000x reference)
//
#include <hip/hip_runtime.h>

// MEASUREMENT ROUND 8. Same lif kernel dispatched 3x:
//   #1 -> d_out  (correctness; also warms x in LLC)   expect 81 us, FETCH~64MiB
//   #2 -> d_ws   (x LLC-warm)                         DECISIVE: 45 us vs 81 us
//   #3 -> d_ws   (steady state)
//   #4 linear copy x->ws (warm-read + HBM-write reference)
// Readout = per-dispatch rocprof rows (dur_us, FETCH_SIZE, WRITE_SIZE).

constexpr int T_STEPS = 64;

typedef float f32x4 __attribute__((ext_vector_type(4)));

__global__ __launch_bounds__(256) void lif_kernel(const f32x4* __restrict__ x,
                                                  f32x4* __restrict__ out,
                                                  int cols4) {
    const int idx = blockIdx.x * blockDim.x + threadIdx.x;
    if (idx >= cols4) return;

    const f32x4* xp = x + idx;
    f32x4* op = out + idx;

    f32x4 v = {0.f, 0.f, 0.f, 0.f};

#pragma unroll 8
    for (int t = 0; t < T_STEPS; ++t) {
        const f32x4 xt = xp[t * cols4];
        const f32x4 h = 0.5f * (v + xt);
        f32x4 s;
        s.x = (h.x >= 1.0f) ? 1.0f : 0.0f;
        s.y = (h.y >= 1.0f) ? 1.0f : 0.0f;
        s.z = (h.z >= 1.0f) ? 1.0f : 0.0f;
        s.w = (h.w >= 1.0f) ? 1.0f : 0.0f;
        v.x = (h.x >= 1.0f) ? 0.0f : h.x;
        v.y = (h.y >= 1.0f) ? 0.0f : h.y;
        v.z = (h.z >= 1.0f) ? 0.0f : h.z;
        v.w = (h.w >= 1.0f) ? 0.0f : h.w;
        __builtin_nontemporal_store(s, op + t * cols4);
    }
}

__global__ __launch_bounds__(256) void probe_copy(const f32x4* __restrict__ x,
                                                  f32x4* __restrict__ ws,
                                                  int n4) {
    const int stride = gridDim.x * blockDim.x;
    for (int i = blockIdx.x * blockDim.x + threadIdx.x; i < n4; i += stride)
        __builtin_nontemporal_store(x[i], &ws[i]);
}

extern "C" void kernel_launch(void* const* d_in, const int* in_sizes, int n_in,
                              void* d_out, int out_size, void* d_ws, size_t ws_size,
                              hipStream_t stream) {
    const float* x = (const float*)d_in[0];
    float* out = (float*)d_out;

    const int total = in_sizes[0];            // T * B * N
    const int cols = total / T_STEPS;         // B * N
    const int cols4 = cols / 4;               // 131072
    const int total4 = total / 4;             // 8388608 (128 MiB of f32x4)

    const int block = 256;
    const int grid = (cols4 + block - 1) / block;

    // #1 real output (also warms x in LLC)
    lif_kernel<<<grid, block, 0, stream>>>((const f32x4*)x, (f32x4*)out, cols4);

    // #2, #3 identical work into scratch: x is now LLC-warm.
    if (ws_size >= (size_t)total4 * 16) {
        lif_kernel<<<grid, block, 0, stream>>>((const f32x4*)x, (f32x4*)d_ws, cols4);
        lif_kernel<<<grid, block, 0, stream>>>((const f32x4*)x, (f32x4*)d_ws, cols4);
        // #4 warm-read linear copy reference
        probe_copy<<<2048, block, 0, stream>>>((const f32x4*)x, (f32x4*)d_ws, total4);
    }
}

// Round 10
// 241.393 us; speedup vs baseline: 1.4326x; 1.4326x over previous
//
#include <hip/hip_runtime.h>

// LIF recurrence, T=64. x: [T, B*N] f32, out: [T, B*N] f32.
// h=(v+x)/2; s=(h>=1); v=s?0:h.
//
// Round-8 finding: warm-x lif = 40 us (6.3 TB/s fabric ceiling), cold-x = 81 us
// (HBM read-misses mixed into the write stream -> 3.2 TB/s). The poison fills
// evict x before every timed call. Fix: segregate streams -- pass 1 prefetches
// x into LLC at pure-read rate (1 f32x4 touched per 64B line), pass 2 is the
// recurrence running LLC-read + nt-HBM-write at the fabric ceiling.

constexpr int T_STEPS = 64;

typedef float f32x4 __attribute__((ext_vector_type(4)));

// Touch one 16B vector per 64B of x: installs every LLC line with 1/4 of the
// fabric traffic of a full read. acc feeds a never-taken store (no DCE).
__global__ __launch_bounds__(256) void prefetch_x(const f32x4* __restrict__ x,
                                                  float* __restrict__ sink,
                                                  int nlines) {  // nlines = total bytes / 64
    const int stride = gridDim.x * blockDim.x;
    f32x4 acc = {0.f, 0.f, 0.f, 0.f};
    for (int i = blockIdx.x * blockDim.x + threadIdx.x; i < nlines; i += stride)
        acc += x[i * 4];  // one f32x4 per 64B line
    if (acc.x == -1.25e30f && acc.y == 3.77e29f)  // data-dependent, never true
        sink[blockIdx.x] = acc.x + acc.z + acc.w;
}

__global__ __launch_bounds__(256) void lif_kernel(const f32x4* __restrict__ x,
                                                  f32x4* __restrict__ out,
                                                  int cols4) {
    const int idx = blockIdx.x * blockDim.x + threadIdx.x;
    if (idx >= cols4) return;

    const f32x4* xp = x + idx;
    f32x4* op = out + idx;

    f32x4 v = {0.f, 0.f, 0.f, 0.f};

#pragma unroll 8
    for (int t = 0; t < T_STEPS; ++t) {
        const f32x4 xt = xp[t * cols4];
        const f32x4 h = 0.5f * (v + xt);
        f32x4 s;
        s.x = (h.x >= 1.0f) ? 1.0f : 0.0f;
        s.y = (h.y >= 1.0f) ? 1.0f : 0.0f;
        s.z = (h.z >= 1.0f) ? 1.0f : 0.0f;
        s.w = (h.w >= 1.0f) ? 1.0f : 0.0f;
        v.x = (h.x >= 1.0f) ? 0.0f : h.x;
        v.y = (h.y >= 1.0f) ? 0.0f : h.y;
        v.z = (h.z >= 1.0f) ? 0.0f : h.z;
        v.w = (h.w >= 1.0f) ? 0.0f : h.w;
        __builtin_nontemporal_store(s, op + t * cols4);
    }
}

extern "C" void kernel_launch(void* const* d_in, const int* in_sizes, int n_in,
                              void* d_out, int out_size, void* d_ws, size_t ws_size,
                              hipStream_t stream) {
    const float* x = (const float*)d_in[0];
    float* out = (float*)d_out;

    const int total = in_sizes[0];            // T * B * N
    const int cols = total / T_STEPS;         // B * N = 524288
    const int cols4 = cols / 4;               // 131072 f32x4 columns
    const int nlines = total / 16;            // 64B lines in x

    const int block = 256;

    // Pass 1: install x in LLC (read-only stream, ~15-25 us).
    prefetch_x<<<4096, block, 0, stream>>>((const f32x4*)x, (float*)d_ws, nlines);

    // Pass 2: recurrence, LLC-read + nt HBM-write (~40-48 us).
    lif_kernel<<<(cols4 + block - 1) / block, block, 0, stream>>>(
        (const f32x4*)x, (f32x4*)out, cols4);
}